// Round 5
// baseline (766.788 us; speedup 1.0000x reference)
//
#include <hip/hip_runtime.h>

#define T_ 512
#define K_ 128
#define B_ 256

// One block per batch. 512 threads = 8 waves.
// Waves 0-3: forward (logsumexp), waves 4-7: viterbi (max/argmax).
// Thread layout within a role (lin = tid & 255):
//   jg = lin>>2 in [0,64): owns columns j0=2*jg, j1=j0+1
//   c  = lin&3  in [0,4) : owns rows i in [32c, 32c+32)
// Transitions held in 64 registers per thread (exp() of them for forward).
// alpha / viterbi vectors double-buffered in LDS with padded layout
// [4][36] floats (sub-block padding -> the 4 c-groups read disjoint bank
// quads, conflict-free). Emissions prefetched 4 steps ahead in registers
// (t-loop unrolled by 4, static indices). Scale offset S recomputed only
// once per 4-step window (defer-max; drift bound ~32 << fp32 range).
// Backpointers in LDS (uint8, 64KB). One __syncthreads per time step.

#define PADW 36      // dwords per 32-float sub-block (32 + 4 pad)

__global__ __launch_bounds__(512, 2) void crf_main(
    const float* __restrict__ emissions,
    const int* __restrict__ tag_ids,
    const int* __restrict__ lengths,
    const float* __restrict__ transitions,
    float* __restrict__ out,
    float* __restrict__ ws_ll,
    int* __restrict__ ws_cnt)
{
    __shared__ unsigned char bpLDS[T_ * K_];                 // 64 KB backpointers
    __shared__ __align__(16) float eaBuf[2][4 * PADW];       // exp(alpha - S), dbuf, padded
    __shared__ __align__(16) float vaBuf[2][4 * PADW];       // viterbi scores, dbuf, padded
    __shared__ __align__(16) float wmax[4];                  // per-fwd-wave max of alpha
    __shared__ float redLDS[8];                              // score partials
    __shared__ int   redILDS[8];                             // accuracy-count partials
    __shared__ unsigned char decLDS[T_];                     // decoded chain
    __shared__ int ltagLDS;

    const int b   = blockIdx.x;
    const int tid = threadIdx.x;
    const int len = lengths[b];
    const float* emB = emissions + (size_t)b * T_ * K_;
    const int*  tagB = tag_ids + b * T_;

    // ---------------- sequence score (unary + binary), one t per thread ----------------
    {
        int t = tid;                    // blockDim == T_
        float s = 0.f;
        if (t < len) {
            int tg = tagB[t];
            s = emB[t * K_ + tg];
            if (t >= 1) s += transitions[tagB[t - 1] * K_ + tg];
        }
        #pragma unroll
        for (int m = 1; m < 64; m <<= 1) s += __shfl_xor(s, m);
        if ((tid & 63) == 0) redLDS[tid >> 6] = s;
    }

    const int role = tid >> 8;          // 0 = forward, 1 = viterbi
    const int lin  = tid & 255;
    const int jg = lin >> 2;            // column pair 0..63
    const int c  = lin & 3;             // i-range quarter
    const int j0 = 2 * jg;
    // padded write index for columns j0, j0+1 (always same sub-block: j0 even)
    const int wi = (j0 >> 5) * PADW + (j0 & 31);

    // ---------------- per-thread transition block: 32 i x 2 j (registers) ----------------
    float tbl[64];
    if (role == 0) {
        #pragma unroll
        for (int k = 0; k < 32; ++k) {
            float2 tr = *(const float2*)&transitions[(c * 32 + k) * K_ + j0];
            tbl[2 * k + 0] = __expf(tr.x);
            tbl[2 * k + 1] = __expf(tr.y);
        }
    } else {
        #pragma unroll
        for (int k = 0; k < 32; ++k) {
            float2 tr = *(const float2*)&transitions[(c * 32 + k) * K_ + j0];
            tbl[2 * k + 0] = tr.x;
            tbl[2 * k + 1] = tr.y;
        }
    }

    // ---------------- init t = 0 ----------------
    {
        float2 e0 = *(const float2*)(emB + j0);
        if (role == 0) {
            if (c == 0) {
                float2 w2; w2.x = __expf(e0.x); w2.y = __expf(e0.y);   // offset S0 = 0
                *(float2*)&eaBuf[0][wi] = w2;
            }
            float wm = fmaxf(e0.x, e0.y);
            #pragma unroll
            for (int m = 1; m < 64; m <<= 1) wm = fmaxf(wm, __shfl_xor(wm, m));
            if ((lin & 63) == 0) wmax[lin >> 6] = wm;
        } else {
            if (c == 0) *(float2*)&vaBuf[0][wi] = e0;
        }
    }
    __syncthreads();

    // ---------------- main recurrence, unrolled by 4 with emission prefetch ----------------
    int cur = 0;
    float Sr = 0.f;                                   // scale of current ea buffer

    // one full step; TT = position in 4-step window (compile-time)
#define CRF_STEP(T, EMV, TT)                                                   \
    {                                                                          \
        if (role == 0) {                                                       \
            float Sw;                                                          \
            if ((TT) == 0) {                                                   \
                float4 wv = *(const float4*)&wmax[0];                          \
                Sw = fmaxf(fmaxf(wv.x, wv.y), fmaxf(wv.z, wv.w));              \
            } else Sw = Sr;                                                    \
            const float* ea = &eaBuf[cur][c * PADW];                           \
            float a00=0.f,a01=0.f,a02=0.f,a03=0.f;                             \
            float a10=0.f,a11=0.f,a12=0.f,a13=0.f;                             \
            _Pragma("unroll")                                                  \
            for (int mm = 0; mm < 8; ++mm) {                                   \
                float4 e4 = *(const float4*)(ea + 4 * mm);                     \
                a00 = fmaf(e4.x, tbl[8*mm+0], a00);                            \
                a10 = fmaf(e4.x, tbl[8*mm+1], a10);                            \
                a01 = fmaf(e4.y, tbl[8*mm+2], a01);                            \
                a11 = fmaf(e4.y, tbl[8*mm+3], a11);                            \
                a02 = fmaf(e4.z, tbl[8*mm+4], a02);                            \
                a12 = fmaf(e4.z, tbl[8*mm+5], a12);                            \
                a03 = fmaf(e4.w, tbl[8*mm+6], a03);                            \
                a13 = fmaf(e4.w, tbl[8*mm+7], a13);                            \
            }                                                                  \
            float d0 = (a00 + a01) + (a02 + a03);                              \
            float d1 = (a10 + a11) + (a12 + a13);                              \
            d0 += __shfl_xor(d0, 1); d0 += __shfl_xor(d0, 2);                  \
            d1 += __shfl_xor(d1, 1); d1 += __shfl_xor(d1, 2);                  \
            float an0 = __logf(d0) + Sr + (EMV).x;                             \
            float an1 = __logf(d1) + Sr + (EMV).y;                             \
            if (c == 0) {                                                      \
                float2 w2; w2.x = __expf(an0 - Sw); w2.y = __expf(an1 - Sw);   \
                *(float2*)&eaBuf[cur ^ 1][wi] = w2;                            \
            }                                                                  \
            Sr = Sw;                                                           \
            if ((TT) == 3) {                                                   \
                float wm = fmaxf(an0, an1);                                    \
                _Pragma("unroll")                                              \
                for (int m = 1; m < 64; m <<= 1)                               \
                    wm = fmaxf(wm, __shfl_xor(wm, m));                         \
                if ((lin & 63) == 0) wmax[lin >> 6] = wm;                      \
            }                                                                  \
        } else {                                                               \
            const float* va = &vaBuf[cur][c * PADW];                           \
            float m0 = -3.4028235e38f, m1 = -3.4028235e38f;                    \
            int A0 = c * 32, A1 = c * 32;                                      \
            _Pragma("unroll")                                                  \
            for (int mm = 0; mm < 8; ++mm) {                                   \
                float4 v4 = *(const float4*)(va + 4 * mm);                     \
                float s;                                                       \
                s = v4.x + tbl[8*mm+0]; if (s > m0) { m0 = s; A0 = c*32+4*mm+0; } \
                s = v4.x + tbl[8*mm+1]; if (s > m1) { m1 = s; A1 = c*32+4*mm+0; } \
                s = v4.y + tbl[8*mm+2]; if (s > m0) { m0 = s; A0 = c*32+4*mm+1; } \
                s = v4.y + tbl[8*mm+3]; if (s > m1) { m1 = s; A1 = c*32+4*mm+1; } \
                s = v4.z + tbl[8*mm+4]; if (s > m0) { m0 = s; A0 = c*32+4*mm+2; } \
                s = v4.z + tbl[8*mm+5]; if (s > m1) { m1 = s; A1 = c*32+4*mm+2; } \
                s = v4.w + tbl[8*mm+6]; if (s > m0) { m0 = s; A0 = c*32+4*mm+3; } \
                s = v4.w + tbl[8*mm+7]; if (s > m1) { m1 = s; A1 = c*32+4*mm+3; } \
            }                                                                  \
            /* combine across c: global index compare = first-max-wins */      \
            _Pragma("unroll")                                                  \
            for (int sft = 1; sft <= 2; sft <<= 1) {                           \
                float o0 = __shfl_xor(m0, sft); int b0 = __shfl_xor(A0, sft);  \
                if (o0 > m0 || (o0 == m0 && b0 < A0)) { m0 = o0; A0 = b0; }    \
                float o1 = __shfl_xor(m1, sft); int b1 = __shfl_xor(A1, sft);  \
                if (o1 > m1 || (o1 == m1 && b1 < A1)) { m1 = o1; A1 = b1; }    \
            }                                                                  \
            if (c == 0) {                                                      \
                float2 nv; nv.x = m0 + (EMV).x; nv.y = m1 + (EMV).y;           \
                *(float2*)&vaBuf[cur ^ 1][wi] = nv;                            \
                *(unsigned short*)&bpLDS[(T) * K_ + j0] =                      \
                    (unsigned short)((A0 & 0xff) | ((A1 & 0xff) << 8));        \
            }                                                                  \
        }                                                                      \
        cur ^= 1;                                                              \
        __syncthreads();                                                       \
    }

    // prologue: emissions for t = 1..4 (always in-bounds: T_ = 512)
    float2 eA0 = *(const float2*)(emB + 1 * K_ + j0);
    float2 eA1 = *(const float2*)(emB + 2 * K_ + j0);
    float2 eA2 = *(const float2*)(emB + 3 * K_ + j0);
    float2 eA3 = *(const float2*)(emB + 4 * K_ + j0);

    for (int tw = 1; tw < len; tw += 4) {
        // prefetch next window's emissions (clamped; dead steps never consume)
        int tp = tw + 4;
        int p0 = tp     < T_ ? tp     : T_ - 1;
        int p1 = tp + 1 < T_ ? tp + 1 : T_ - 1;
        int p2 = tp + 2 < T_ ? tp + 2 : T_ - 1;
        int p3 = tp + 3 < T_ ? tp + 3 : T_ - 1;
        float2 eB0 = *(const float2*)(emB + p0 * K_ + j0);
        float2 eB1 = *(const float2*)(emB + p1 * K_ + j0);
        float2 eB2 = *(const float2*)(emB + p2 * K_ + j0);
        float2 eB3 = *(const float2*)(emB + p3 * K_ + j0);

        CRF_STEP(tw, eA0, 0);
        if (tw + 1 < len) CRF_STEP(tw + 1, eA1, 1);
        if (tw + 2 < len) CRF_STEP(tw + 2, eA2, 2);
        if (tw + 3 < len) CRF_STEP(tw + 3, eA3, 3);

        eA0 = eB0; eA1 = eB1; eA2 = eB2; eA3 = eB3;
    }
#undef CRF_STEP

    // ---------------- logZ (forward wave 0) ----------------
    float logZv = 0.f;
    if (tid < 64) {
        float s = eaBuf[cur][(tid >> 5) * PADW + (tid & 31)]
                + eaBuf[cur][((tid + 64) >> 5) * PADW + ((tid + 64) & 31)];
        #pragma unroll
        for (int m = 1; m < 64; m <<= 1) s += __shfl_xor(s, m);
        logZv = Sr + __logf(s);                       // valid in lane 0 (tid 0)
    }

    // ---------------- last tag: argmax_j v_final (first-max-wins) ----------------
    if (tid >= 256 && tid < 320) {
        int l = tid - 256;
        float m = vaBuf[cur][(l >> 5) * PADW + (l & 31)];
        int a = l;
        float v2 = vaBuf[cur][((l + 64) >> 5) * PADW + ((l + 64) & 31)];
        if (v2 > m) { m = v2; a = l + 64; }
        #pragma unroll
        for (int sft = 1; sft < 64; sft <<= 1) {
            float om = __shfl_xor(m, sft);
            int   oa = __shfl_xor(a, sft);
            if (om > m || (om == m && oa < a)) { m = om; a = oa; }
        }
        if (l == 0) ltagLDS = a;
    }
    __syncthreads();

    // ---------------- backtrace (serial chain through LDS) ----------------
    if (tid == 0) {
        int tg = ltagLDS;
        for (int t = T_ - 1; t >= 1; --t) {
            decLDS[t] = (unsigned char)tg;
            if (t < len) tg = bpLDS[t * K_ + tg];     // identity bp for t >= len
        }
        decLDS[0] = (unsigned char)tg;
    }
    __syncthreads();

    // ---------------- decoded write + accuracy count ----------------
    {
        int t = tid;
        int dv = decLDS[t];
        out[1 + b * T_ + t] = (float)dv;
        int good = (t < len && tagB[t] == dv) ? 1 : 0;
        #pragma unroll
        for (int m = 1; m < 64; m <<= 1) good += __shfl_xor(good, m);
        if ((tid & 63) == 0) redILDS[tid >> 6] = good;
    }
    __syncthreads();

    if (tid == 0) {
        float sc = 0.f; int cnt = 0;
        #pragma unroll
        for (int w = 0; w < 8; ++w) { sc += redLDS[w]; cnt += redILDS[w]; }
        ws_ll[b]  = sc - logZv;                       // log-likelihood of batch b
        ws_cnt[b] = cnt;
    }
}

// Final reduction: loss = -mean(ll), accuracy = sum(correct)/sum(len)
__global__ void crf_final(const float* __restrict__ ws_ll,
                          const int* __restrict__ ws_cnt,
                          const int* __restrict__ lengths,
                          float* __restrict__ out)
{
    __shared__ float sll[4];
    __shared__ int scnt[4], slen[4];
    int tid = threadIdx.x;                            // blockDim == B_ == 256
    float ll = ws_ll[tid];
    int   cn = ws_cnt[tid];
    int   L  = lengths[tid];
    #pragma unroll
    for (int m = 1; m < 64; m <<= 1) {
        ll += __shfl_xor(ll, m);
        cn += __shfl_xor(cn, m);
        L  += __shfl_xor(L, m);
    }
    if ((tid & 63) == 0) { sll[tid >> 6] = ll; scnt[tid >> 6] = cn; slen[tid >> 6] = L; }
    __syncthreads();
    if (tid == 0) {
        float llS = sll[0] + sll[1] + sll[2] + sll[3];
        int   cS  = scnt[0] + scnt[1] + scnt[2] + scnt[3];
        int   LS  = slen[0] + slen[1] + slen[2] + slen[3];
        out[0] = -llS / (float)B_;
        out[1 + B_ * T_] = (float)cS / (float)LS;
    }
}

extern "C" void kernel_launch(void* const* d_in, const int* in_sizes, int n_in,
                              void* d_out, int out_size, void* d_ws, size_t ws_size,
                              hipStream_t stream) {
    const float* emissions   = (const float*)d_in[0];
    const int*   tag_ids     = (const int*)d_in[1];
    const int*   lengths     = (const int*)d_in[2];
    const float* transitions = (const float*)d_in[3];
    float* out = (float*)d_out;

    float* ws_ll  = (float*)d_ws;
    int*   ws_cnt = (int*)((char*)d_ws + B_ * sizeof(float));

    crf_main<<<B_, 512, 0, stream>>>(emissions, tag_ids, lengths, transitions,
                                     out, ws_ll, ws_cnt);
    crf_final<<<1, B_, 0, stream>>>(ws_ll, ws_cnt, lengths, out);
}

// Round 8
// 614.068 us; speedup vs baseline: 1.2487x; 1.2487x over previous
//
#include <hip/hip_runtime.h>

#define T_ 512
#define K_ 128
#define B_ 256

// Role-split grid: blocks [0,256) = forward (logsumexp + logZ + sequence score),
// blocks [256,512) = viterbi (argmax recurrence + backtrace + accuracy).
// The two recurrences are semantically independent; giving each its own block
// removes 511 heterogeneous 8-wave rendezvous (the R5 counters showed the step
// cost ~3270 cyc vs ~1000 cyc of issue -> barrier coupling dominated).
//
// Per-role layout (256 threads = 4 waves, baseline-proven c-split-2):
//   j = tid>>1 in [0,128): output column; c = tid&1: i-half [64c, 64c+64)
//   tbl[64] per thread: transitions[64c+k][j] (exp() of it for forward)
// One __syncthreads per step across 4 homogeneous waves.
// Forward rescale offset recomputed once per 4 steps (defer-max, verified
// absmax 0.0 in R5). Emission for step t+1 prefetched distance-1.

__global__ __launch_bounds__(256, 2) void crf_main(
    const float* __restrict__ emissions,
    const int* __restrict__ tag_ids,
    const int* __restrict__ lengths,
    const float* __restrict__ transitions,
    float* __restrict__ out,
    float* __restrict__ ws_ll,
    int* __restrict__ ws_cnt)
{
    const int bid = blockIdx.x;
    const int tid = threadIdx.x;

    if (bid < B_) {
        // ==================== FORWARD block ====================
        __shared__ __align__(16) float eaBuf[2][K_];   // exp(alpha - S), dbuf
        __shared__ __align__(16) float wmax[4];        // per-wave max of alpha
        __shared__ float redLDS[4];                    // score partials

        const int b   = bid;
        const int len = lengths[b];
        const float* emB = emissions + (size_t)b * T_ * K_;
        const int*  tagB = tag_ids + b * T_;

        // ---- sequence score (unary + binary), 2 t per thread ----
        {
            float s = 0.f;
            #pragma unroll
            for (int h = 0; h < 2; ++h) {
                int t = tid + h * 256;
                if (t < len) {
                    int tg = tagB[t];
                    float v = emB[t * K_ + tg];
                    if (t >= 1) v += transitions[tagB[t - 1] * K_ + tg];
                    s += v;
                }
            }
            #pragma unroll
            for (int m = 1; m < 64; m <<= 1) s += __shfl_xor(s, m);
            if ((tid & 63) == 0) redLDS[tid >> 6] = s;
        }

        const int j = tid >> 1;
        const int c = tid & 1;

        float tbl[64];
        #pragma unroll
        for (int k = 0; k < 64; ++k)
            tbl[k] = __expf(transitions[(c * 64 + k) * K_ + j]);

        // ---- init t = 0 (offset S0 = 0) ----
        {
            float e0 = emB[j];
            if (c == 0) eaBuf[0][j] = __expf(e0);
            float wm = e0;
            #pragma unroll
            for (int m = 1; m < 64; m <<= 1) wm = fmaxf(wm, __shfl_xor(wm, m));
            if ((tid & 63) == 0) wmax[tid >> 6] = wm;
        }
        __syncthreads();

        int cur = 0;
        float Sr = 0.f;                                // scale of current ea buffer
        float emN = emB[K_ + j];                       // prefetch t = 1

        for (int t = 1; t < len; ++t) {
            float emC = emN;
            int tn = (t + 1 < T_) ? (t + 1) : t;
            emN = emB[tn * K_ + j];                    // issue early, consume next step

            float Sw;
            if (((t - 1) & 3) == 0) {                  // window start: fresh scale
                float4 wv = *(const float4*)&wmax[0];
                Sw = fmaxf(fmaxf(wv.x, wv.y), fmaxf(wv.z, wv.w));
            } else Sw = Sr;

            const float* ea = &eaBuf[cur][c * 64];
            float a0 = 0.f, a1 = 0.f, a2 = 0.f, a3 = 0.f;
            #pragma unroll
            for (int k = 0; k < 16; ++k) {
                float4 e4 = *(const float4*)(ea + 4 * k);
                a0 = fmaf(e4.x, tbl[4 * k + 0], a0);
                a1 = fmaf(e4.y, tbl[4 * k + 1], a1);
                a2 = fmaf(e4.z, tbl[4 * k + 2], a2);
                a3 = fmaf(e4.w, tbl[4 * k + 3], a3);
            }
            float dot = (a0 + a1) + (a2 + a3);
            dot += __shfl_xor(dot, 1);                 // combine the two i-halves

            float an = __logf(dot) + Sr + emC;
            if (c == 0) eaBuf[cur ^ 1][j] = __expf(an - Sw);
            Sr = Sw;

            if (((t - 1) & 3) == 3) {                  // window end: publish max
                float wm = an;
                #pragma unroll
                for (int m = 1; m < 64; m <<= 1) wm = fmaxf(wm, __shfl_xor(wm, m));
                if ((tid & 63) == 0) wmax[tid >> 6] = wm;
            }
            cur ^= 1;
            __syncthreads();
        }

        // ---- logZ + final write ----
        float logZv = 0.f;
        if (tid < 64) {
            float s = eaBuf[cur][tid] + eaBuf[cur][tid + 64];
            #pragma unroll
            for (int m = 1; m < 64; m <<= 1) s += __shfl_xor(s, m);
            logZv = Sr + __logf(s);                    // valid in tid 0
        }
        if (tid == 0) {
            float sc = redLDS[0] + redLDS[1] + redLDS[2] + redLDS[3];
            ws_ll[b] = sc - logZv;
        }

    } else {
        // ==================== VITERBI block ====================
        __shared__ unsigned char bpLDS[T_ * K_];       // 64 KB backpointers
        __shared__ __align__(16) float vaBuf[2][K_];   // viterbi scores, dbuf
        __shared__ unsigned char decLDS[T_];           // decoded chain
        __shared__ int redILDS[4];                     // accuracy partials
        __shared__ int ltagLDS;

        const int b   = bid - B_;
        const int len = lengths[b];
        const float* emB = emissions + (size_t)b * T_ * K_;
        const int*  tagB = tag_ids + b * T_;

        const int j = tid >> 1;
        const int c = tid & 1;

        float tbl[64];
        #pragma unroll
        for (int k = 0; k < 64; ++k)
            tbl[k] = transitions[(c * 64 + k) * K_ + j];

        // ---- init t = 0 ----
        {
            float e0 = emB[j];
            if (c == 0) vaBuf[0][j] = e0;
        }
        __syncthreads();

        int cur = 0;
        float emN = emB[K_ + j];                       // prefetch t = 1

        for (int t = 1; t < len; ++t) {
            float emC = emN;
            int tn = (t + 1 < T_) ? (t + 1) : t;
            emN = emB[tn * K_ + j];

            const float* va = &vaBuf[cur][c * 64];
            float mB = -3.4028235e38f;
            int arg = 0;
            #pragma unroll
            for (int k = 0; k < 16; ++k) {             // ascending i: first-max-wins
                float4 v4 = *(const float4*)(va + 4 * k);
                float s0 = v4.x + tbl[4 * k + 0]; if (s0 > mB) { mB = s0; arg = 4 * k + 0; }
                float s1 = v4.y + tbl[4 * k + 1]; if (s1 > mB) { mB = s1; arg = 4 * k + 1; }
                float s2 = v4.z + tbl[4 * k + 2]; if (s2 > mB) { mB = s2; arg = 4 * k + 2; }
                float s3 = v4.w + tbl[4 * k + 3]; if (s3 > mB) { mB = s3; arg = 4 * k + 3; }
            }
            arg += c * 64;
            float om = __shfl_xor(mB, 1);
            int   oa = __shfl_xor(arg, 1);
            // low-i half wins ties
            float mLow  = c ? om : mB;   int aLow  = c ? oa : arg;
            float mHigh = c ? mB : om;   int aHigh = c ? arg : oa;
            float mF; int aF;
            if (mHigh > mLow) { mF = mHigh; aF = aHigh; } else { mF = mLow; aF = aLow; }
            if (c == 0) {
                vaBuf[cur ^ 1][j] = mF + emC;
                bpLDS[t * K_ + j] = (unsigned char)aF;
            }
            cur ^= 1;
            __syncthreads();
        }

        // ---- last tag: argmax_j v_final (first-max-wins) ----
        if (tid < 64) {
            int l = tid;
            float m = vaBuf[cur][l]; int a = l;
            float v2 = vaBuf[cur][l + 64];
            if (v2 > m) { m = v2; a = l + 64; }
            #pragma unroll
            for (int sft = 1; sft < 64; sft <<= 1) {
                float om = __shfl_xor(m, sft);
                int   oa = __shfl_xor(a, sft);
                if (om > m || (om == m && oa < a)) { m = om; a = oa; }
            }
            if (l == 0) ltagLDS = a;
        }
        __syncthreads();

        // ---- backtrace (serial chain through LDS) ----
        if (tid == 0) {
            int tg = ltagLDS;
            for (int t = T_ - 1; t >= 1; --t) {
                decLDS[t] = (unsigned char)tg;
                if (t < len) tg = bpLDS[t * K_ + tg];  // identity bp for t >= len
            }
            decLDS[0] = (unsigned char)tg;
        }
        __syncthreads();

        // ---- decoded write + accuracy count, 2 t per thread ----
        {
            int good = 0;
            #pragma unroll
            for (int h = 0; h < 2; ++h) {
                int t = tid + h * 256;
                int dv = decLDS[t];
                out[1 + b * T_ + t] = (float)dv;
                good += (t < len && tagB[t] == dv) ? 1 : 0;
            }
            #pragma unroll
            for (int m = 1; m < 64; m <<= 1) good += __shfl_xor(good, m);
            if ((tid & 63) == 0) redILDS[tid >> 6] = good;
        }
        __syncthreads();

        if (tid == 0)
            ws_cnt[b] = redILDS[0] + redILDS[1] + redILDS[2] + redILDS[3];
    }
}

// Final reduction: loss = -mean(ll), accuracy = sum(correct)/sum(len)
__global__ void crf_final(const float* __restrict__ ws_ll,
                          const int* __restrict__ ws_cnt,
                          const int* __restrict__ lengths,
                          float* __restrict__ out)
{
    __shared__ float sll[4];
    __shared__ int scnt[4], slen[4];
    int tid = threadIdx.x;                            // blockDim == B_ == 256
    float ll = ws_ll[tid];
    int   cn = ws_cnt[tid];
    int   L  = lengths[tid];
    #pragma unroll
    for (int m = 1; m < 64; m <<= 1) {
        ll += __shfl_xor(ll, m);
        cn += __shfl_xor(cn, m);
        L  += __shfl_xor(L, m);
    }
    if ((tid & 63) == 0) { sll[tid >> 6] = ll; scnt[tid >> 6] = cn; slen[tid >> 6] = L; }
    __syncthreads();
    if (tid == 0) {
        float llS = sll[0] + sll[1] + sll[2] + sll[3];
        int   cS  = scnt[0] + scnt[1] + scnt[2] + scnt[3];
        int   LS  = slen[0] + slen[1] + slen[2] + slen[3];
        out[0] = -llS / (float)B_;
        out[1 + B_ * T_] = (float)cS / (float)LS;
    }
}

extern "C" void kernel_launch(void* const* d_in, const int* in_sizes, int n_in,
                              void* d_out, int out_size, void* d_ws, size_t ws_size,
                              hipStream_t stream) {
    const float* emissions   = (const float*)d_in[0];
    const int*   tag_ids     = (const int*)d_in[1];
    const int*   lengths     = (const int*)d_in[2];
    const float* transitions = (const float*)d_in[3];
    float* out = (float*)d_out;

    float* ws_ll  = (float*)d_ws;
    int*   ws_cnt = (int*)((char*)d_ws + B_ * sizeof(float));

    crf_main<<<2 * B_, 256, 0, stream>>>(emissions, tag_ids, lengths, transitions,
                                         out, ws_ll, ws_cnt);
    crf_final<<<1, B_, 0, stream>>>(ws_ll, ws_cnt, lengths, out);
}

// Round 10
// 565.187 us; speedup vs baseline: 1.3567x; 1.0865x over previous
//
#include <hip/hip_runtime.h>

#define T_ 512
#define K_ 128
#define B_ 256
#define PADH 68      // dword stride between i-halves (64 + 4 skew, 16B-aligned)

// Role-split grid: blocks [0,256) = forward, blocks [256,512) = viterbi.
// (R8: role-split measured 697 -> 548 us; counters showed 3.09e7 LDS bank
// conflicts + long viterbi dependency chain as the residual.)
//
// Layout per role block (256 thr = 4 waves): j = tid>>1, c = tid&1.
// State buffers skewed: half c stored at dword offset c*PADH; instruction k
// reads bank-quad 4k (c=0) vs 4k+4 (c=1) -> disjoint banks, pure broadcast,
// zero conflicts. Viterbi argmax is a tournament tree (first-max-wins at
// every level == jnp.argmax semantics), dep depth ~6 levels instead of 64.

__global__ __launch_bounds__(256, 2) void crf_main(
    const float* __restrict__ emissions,
    const int* __restrict__ tag_ids,
    const int* __restrict__ lengths,
    const float* __restrict__ transitions,
    float* __restrict__ out,
    float* __restrict__ ws_ll,
    int* __restrict__ ws_cnt)
{
    const int bid = blockIdx.x;
    const int tid = threadIdx.x;

    if (bid < B_) {
        // ==================== FORWARD block ====================
        __shared__ __align__(16) float eaBuf[2][2 * PADH]; // exp(alpha-S), skewed dbuf
        __shared__ __align__(16) float wmax[4];            // per-wave max of alpha
        __shared__ float redLDS[4];                        // score partials

        const int b   = bid;
        const int len = lengths[b];
        const float* emB = emissions + (size_t)b * T_ * K_;
        const int*  tagB = tag_ids + b * T_;

        // ---- sequence score (unary + binary), 2 t per thread ----
        {
            float s = 0.f;
            #pragma unroll
            for (int h = 0; h < 2; ++h) {
                int t = tid + h * 256;
                if (t < len) {
                    int tg = tagB[t];
                    float v = emB[t * K_ + tg];
                    if (t >= 1) v += transitions[tagB[t - 1] * K_ + tg];
                    s += v;
                }
            }
            #pragma unroll
            for (int m = 1; m < 64; m <<= 1) s += __shfl_xor(s, m);
            if ((tid & 63) == 0) redLDS[tid >> 6] = s;
        }

        const int j = tid >> 1;
        const int c = tid & 1;
        const int wiA = (j >> 6) * PADH + (j & 63);        // skewed write index

        float tbl[64];
        #pragma unroll
        for (int k = 0; k < 64; ++k)
            tbl[k] = __expf(transitions[(c * 64 + k) * K_ + j]);

        // ---- init t = 0 (offset S0 = 0) ----
        {
            float e0 = emB[j];
            if (c == 0) eaBuf[0][wiA] = __expf(e0);
            float wm = e0;
            #pragma unroll
            for (int m = 1; m < 64; m <<= 1) wm = fmaxf(wm, __shfl_xor(wm, m));
            if ((tid & 63) == 0) wmax[tid >> 6] = wm;
        }
        __syncthreads();

        int cur = 0;
        float Sr = 0.f;                                // scale of current ea buffer
        float emN = emB[K_ + j];                       // prefetch t = 1

        for (int t = 1; t < len; ++t) {
            float emC = emN;
            int tn = (t + 1 < T_) ? (t + 1) : t;
            emN = emB[tn * K_ + j];                    // issue early, consume next step

            float Sw;
            if (((t - 1) & 3) == 0) {                  // window start: fresh scale
                float4 wv = *(const float4*)&wmax[0];
                Sw = fmaxf(fmaxf(wv.x, wv.y), fmaxf(wv.z, wv.w));
            } else Sw = Sr;

            const float* ea = &eaBuf[cur][c * PADH];
            float a0 = 0.f, a1 = 0.f, a2 = 0.f, a3 = 0.f;
            #pragma unroll
            for (int k = 0; k < 16; ++k) {
                float4 e4 = *(const float4*)(ea + 4 * k);
                a0 = fmaf(e4.x, tbl[4 * k + 0], a0);
                a1 = fmaf(e4.y, tbl[4 * k + 1], a1);
                a2 = fmaf(e4.z, tbl[4 * k + 2], a2);
                a3 = fmaf(e4.w, tbl[4 * k + 3], a3);
            }
            float dot = (a0 + a1) + (a2 + a3);
            dot += __shfl_xor(dot, 1);                 // combine the two i-halves

            float an = __logf(dot) + Sr + emC;
            if (c == 0) eaBuf[cur ^ 1][wiA] = __expf(an - Sw);
            Sr = Sw;

            if (((t - 1) & 3) == 3) {                  // window end: publish max
                float wm = an;
                #pragma unroll
                for (int m = 1; m < 64; m <<= 1) wm = fmaxf(wm, __shfl_xor(wm, m));
                if ((tid & 63) == 0) wmax[tid >> 6] = wm;
            }
            cur ^= 1;
            __syncthreads();
        }

        // ---- logZ + final write ----
        float logZv = 0.f;
        if (tid < 64) {
            float s = eaBuf[cur][tid] + eaBuf[cur][PADH + tid];
            #pragma unroll
            for (int m = 1; m < 64; m <<= 1) s += __shfl_xor(s, m);
            logZv = Sr + __logf(s);                    // valid in tid 0
        }
        if (tid == 0) {
            float sc = redLDS[0] + redLDS[1] + redLDS[2] + redLDS[3];
            ws_ll[b] = sc - logZv;
        }

    } else {
        // ==================== VITERBI block ====================
        __shared__ unsigned char bpLDS[T_ * K_];           // 64 KB backpointers
        __shared__ __align__(16) float vaBuf[2][2 * PADH]; // skewed dbuf
        __shared__ unsigned char decLDS[T_];               // decoded chain
        __shared__ int redILDS[4];                         // accuracy partials
        __shared__ int ltagLDS;

        const int b   = bid - B_;
        const int len = lengths[b];
        const float* emB = emissions + (size_t)b * T_ * K_;
        const int*  tagB = tag_ids + b * T_;

        const int j = tid >> 1;
        const int c = tid & 1;
        const int wiA = (j >> 6) * PADH + (j & 63);

        float tbl[64];
        #pragma unroll
        for (int k = 0; k < 64; ++k)
            tbl[k] = transitions[(c * 64 + k) * K_ + j];

        // ---- init t = 0 ----
        {
            float e0 = emB[j];
            if (c == 0) vaBuf[0][wiA] = e0;
        }
        __syncthreads();

        int cur = 0;
        float emN = emB[K_ + j];                       // prefetch t = 1

        for (int t = 1; t < len; ++t) {
            float emC = emN;
            int tn = (t + 1 < T_) ? (t + 1) : t;
            emN = emB[tn * K_ + j];

            const float* va = &vaBuf[cur][c * PADH];
            // tournament argmax: 16 independent group winners, then 4-level
            // tree; "take right only if strictly greater" at every level ==
            // lowest-index-among-maxima == first-max-wins.
            float v0[16];
            int   g0[16];
            #pragma unroll
            for (int k = 0; k < 16; ++k) {
                float4 v4 = *(const float4*)(va + 4 * k);
                float s0 = v4.x + tbl[4 * k + 0];
                float s1 = v4.y + tbl[4 * k + 1];
                float s2 = v4.z + tbl[4 * k + 2];
                float s3 = v4.w + tbl[4 * k + 3];
                float mA; int aA;
                if (s1 > s0) { mA = s1; aA = 4 * k + 1; } else { mA = s0; aA = 4 * k + 0; }
                float mC; int aC;
                if (s3 > s2) { mC = s3; aC = 4 * k + 3; } else { mC = s2; aC = 4 * k + 2; }
                if (mC > mA) { v0[k] = mC; g0[k] = aC; } else { v0[k] = mA; g0[k] = aA; }
            }
            #pragma unroll
            for (int st = 1; st < 16; st <<= 1) {
                #pragma unroll
                for (int k = 0; k < 16; k += 2 * st) {
                    if (v0[k + st] > v0[k]) { v0[k] = v0[k + st]; g0[k] = g0[k + st]; }
                }
            }
            float mB = v0[0];
            int  arg = g0[0] + c * 64;

            float om = __shfl_xor(mB, 1);
            int   oa = __shfl_xor(arg, 1);
            // low-i half wins ties
            float mLow  = c ? om : mB;   int aLow  = c ? oa : arg;
            float mHigh = c ? mB : om;   int aHigh = c ? arg : oa;
            float mF; int aF;
            if (mHigh > mLow) { mF = mHigh; aF = aHigh; } else { mF = mLow; aF = aLow; }
            if (c == 0) {
                vaBuf[cur ^ 1][wiA] = mF + emC;
                bpLDS[t * K_ + j] = (unsigned char)aF;
            }
            cur ^= 1;
            __syncthreads();
        }

        // ---- last tag: argmax_j v_final (first-max-wins) ----
        if (tid < 64) {
            int l = tid;
            float m = vaBuf[cur][l]; int a = l;
            float v2 = vaBuf[cur][PADH + l];
            if (v2 > m) { m = v2; a = l + 64; }
            #pragma unroll
            for (int sft = 1; sft < 64; sft <<= 1) {
                float om = __shfl_xor(m, sft);
                int   oa = __shfl_xor(a, sft);
                if (om > m || (om == m && oa < a)) { m = om; a = oa; }
            }
            if (l == 0) ltagLDS = a;
        }
        __syncthreads();

        // ---- backtrace (serial chain through LDS) ----
        if (tid == 0) {
            int tg = ltagLDS;
            for (int t = T_ - 1; t >= 1; --t) {
                decLDS[t] = (unsigned char)tg;
                if (t < len) tg = bpLDS[t * K_ + tg];  // identity bp for t >= len
            }
            decLDS[0] = (unsigned char)tg;
        }
        __syncthreads();

        // ---- decoded write + accuracy count, 2 t per thread ----
        {
            int good = 0;
            #pragma unroll
            for (int h = 0; h < 2; ++h) {
                int t = tid + h * 256;
                int dv = decLDS[t];
                out[1 + b * T_ + t] = (float)dv;
                good += (t < len && tagB[t] == dv) ? 1 : 0;
            }
            #pragma unroll
            for (int m = 1; m < 64; m <<= 1) good += __shfl_xor(good, m);
            if ((tid & 63) == 0) redILDS[tid >> 6] = good;
        }
        __syncthreads();

        if (tid == 0)
            ws_cnt[b] = redILDS[0] + redILDS[1] + redILDS[2] + redILDS[3];
    }
}

// Final reduction: loss = -mean(ll), accuracy = sum(correct)/sum(len)
__global__ void crf_final(const float* __restrict__ ws_ll,
                          const int* __restrict__ ws_cnt,
                          const int* __restrict__ lengths,
                          float* __restrict__ out)
{
    __shared__ float sll[4];
    __shared__ int scnt[4], slen[4];
    int tid = threadIdx.x;                            // blockDim == B_ == 256
    float ll = ws_ll[tid];
    int   cn = ws_cnt[tid];
    int   L  = lengths[tid];
    #pragma unroll
    for (int m = 1; m < 64; m <<= 1) {
        ll += __shfl_xor(ll, m);
        cn += __shfl_xor(cn, m);
        L  += __shfl_xor(L, m);
    }
    if ((tid & 63) == 0) { sll[tid >> 6] = ll; scnt[tid >> 6] = cn; slen[tid >> 6] = L; }
    __syncthreads();
    if (tid == 0) {
        float llS = sll[0] + sll[1] + sll[2] + sll[3];
        int   cS  = scnt[0] + scnt[1] + scnt[2] + scnt[3];
        int   LS  = slen[0] + slen[1] + slen[2] + slen[3];
        out[0] = -llS / (float)B_;
        out[1 + B_ * T_] = (float)cS / (float)LS;
    }
}

extern "C" void kernel_launch(void* const* d_in, const int* in_sizes, int n_in,
                              void* d_out, int out_size, void* d_ws, size_t ws_size,
                              hipStream_t stream) {
    const float* emissions   = (const float*)d_in[0];
    const int*   tag_ids     = (const int*)d_in[1];
    const int*   lengths     = (const int*)d_in[2];
    const float* transitions = (const float*)d_in[3];
    float* out = (float*)d_out;

    float* ws_ll  = (float*)d_ws;
    int*   ws_cnt = (int*)((char*)d_ws + B_ * sizeof(float));

    crf_main<<<2 * B_, 256, 0, stream>>>(emissions, tag_ids, lengths, transitions,
                                         out, ws_ll, ws_cnt);
    crf_final<<<1, B_, 0, stream>>>(ws_ll, ws_cnt, lengths, out);
}